// Round 12
// baseline (498.339 us; speedup 1.0000x reference)
//
#include <hip/hip_runtime.h>
#include <hip/hip_fp16.h>

static constexpr int NN = 50000;   // nodes
static constexpr int NE = 800000;  // edges
static constexpr int CAP = 64;     // bucket capacity == wave width (Poisson(16) degrees)
static constexpr int NBK1 = 2048;  // k_agg1 grid, grid-stride
static constexpr int NBK2 = 1024;  // k_agg grid, grid-stride
// HID = 64, N_GRAPHS = 64

__device__ __forceinline__ float wsum(float v) {
#pragma unroll
  for (int o = 32; o > 0; o >>= 1) v += __shfl_xor(v, o, 64);
  return v;
}

__device__ __forceinline__ float4 h4tof4(uint2 g) {
  __half2 lo = *(__half2*)&g.x, hi = *(__half2*)&g.y;
  float2 flo = __half22float2(lo), fhi = __half22float2(hi);
  return make_float4(flo.x, flo.y, fhi.x, fhi.y);
}

__device__ __forceinline__ uint2 f4toh4(float4 v) {
  __half2 lo = __float22half2_rn(make_float2(v.x, v.y));
  __half2 hi = __float22half2_rn(make_float2(v.z, v.w));
  uint2 r;
  r.x = *(unsigned*)&lo;
  r.y = *(unsigned*)&hi;
  return r;
}

// one-pass bucketed CSR: slot = atomic rank within dst's bucket (no pre-fill;
// slots >= deg are clamped to -1 at read time -> zero guard row)
__global__ void k_bucket(const int* __restrict__ src, const int* __restrict__ dst,
                         int* __restrict__ cnt, int* __restrict__ bsrc) {
  int e = blockIdx.x * 256 + threadIdx.x;
  if (e < NE) {
    int d = dst[e];
    int p = atomicAdd(&cnt[d], 1);
    if (p < CAP) bsrc[d * CAP + p] = src[e];
  }
}

// xe[v] = dinv[v] * emb[node[v]]  (4-dim, layer-1 aggregation is linear in x)
// + zero guard rows (xe[-1], hA[-64..-1], hB[-64..-1]) + goff binary searches
__global__ void k_embed4(const int* __restrict__ node, const float* __restrict__ emb,
                         const int* __restrict__ cnt, const int* __restrict__ batch,
                         float4* __restrict__ xe, __half* __restrict__ hA,
                         __half* __restrict__ hB, int* __restrict__ goff) {
  int i = blockIdx.x * 256 + threadIdx.x;
  if (i < NN) {
    float dv = rsqrtf((float)cnt[i] + 1.0f);  // deg includes self-loop
    float4 e = ((const float4*)emb)[node[i]];
    e.x *= dv; e.y *= dv; e.z *= dv; e.w *= dv;
    xe[i] = e;
  } else if (i < NN + 64) {
    int j = i - NN;  // guard rows stay zero through all layers
    hA[-64 + j] = __float2half(0.0f);
    hB[-64 + j] = __float2half(0.0f);
    if (j == 0) xe[-1] = make_float4(0.f, 0.f, 0.f, 0.f);
  } else if (i < NN + 129) {  // g in [0,64]: goff[g] = lower_bound(batch, g)
    int g = i - NN - 64;
    int lo = 0, hi = NN;
    while (lo < hi) {
      int mid = (lo + hi) >> 1;
      lo = (batch[mid] < g) ? mid + 1 : lo;
      hi = (batch[mid] < g) ? hi : mid;
    }
    goff[g] = lo;
  }
}

// layer 1: wave-per-node, LANE-PER-EDGE 4-dim gather. Grid-stride: weights
// staged ONCE per block; next node's idx/cnt/self prefetched before current chain.
__global__ void __launch_bounds__(256) k_agg1(
    const float4* __restrict__ xe, __half* __restrict__ ho,
    const int* __restrict__ cnt, const int* __restrict__ bsrc,
    const float* __restrict__ W1, const float* __restrict__ b1,
    const float* __restrict__ g1, const float* __restrict__ lb1,
    const float* __restrict__ W2) {
  __shared__ float W1s[256];
  __shared__ float Wl[4096];
  __shared__ float xs[256];
  int t = threadIdx.x;
  W1s[t] = W1[t];
  for (int i = t; i < 4096; i += 256) Wl[i] = W2[i];
  __syncthreads();
  int w = t >> 6, lane = t & 63;
  int v = blockIdx.x * 4 + w;  // stride NBK1*4 = 8192
  int uu = bsrc[v * CAP + lane];
  int ct = __builtin_amdgcn_readfirstlane(cnt[v]);
  float4 sv = xe[(long)v];
  while (true) {
    int vn = v + NBK1 * 4;
    bool more = vn < NN;  // wave-uniform
    int uun = 0, ctn = 0;
    float4 svn;
    if (more) {  // prefetch next iteration ahead of current dependency chain
      uun = bsrc[vn * CAP + lane];
      ctn = __builtin_amdgcn_readfirstlane(cnt[vn]);
      svn = xe[(long)vn];
    }
    int deg = min(ct, CAP);
    int u = (lane < deg) ? uu : -1;      // clamp garbage slots -> zero guard row
    float4 y = xe[(long)u];              // 64 scattered 16B gathers in ONE instruction
#pragma unroll
    for (int o = 32; o > 0; o >>= 1) {   // wave-reduce float4
      y.x += __shfl_xor(y.x, o, 64);
      y.y += __shfl_xor(y.y, o, 64);
      y.z += __shfl_xor(y.z, o, 64);
      y.w += __shfl_xor(y.w, o, 64);
    }
    float dv = rsqrtf((float)ct + 1.0f);
    y.x = dv * (y.x + sv.x);
    y.y = dv * (y.y + sv.y);
    y.z = dv * (y.z + sv.z);
    y.w = dv * (y.w + sv.w);
    float val = y.x * W1s[lane] + y.y * W1s[64 + lane] + y.z * W1s[128 + lane] +
                y.w * W1s[192 + lane] + b1[lane];
    val = fmaxf(val, 0.0f);  // relu
    float mu = wsum(val) * 0.015625f;
    float d = val - mu;
    float var = wsum(d * d) * 0.015625f;
    val = d * rsqrtf(var + 1e-5f) * g1[lane] + lb1[lane];
    xs[w * 64 + lane] = val;  // broadcast x for W2 transform (per-wave slot)
    float hn = 0.0f;
    const float* xp = &xs[w * 64];
#pragma unroll
    for (int k0 = 0; k0 < 64; k0 += 4) {
      float4 xv = *(const float4*)(xp + k0);  // wave-uniform addr -> broadcast
      hn += xv.x * Wl[(k0 + 0) * 64 + lane];
      hn += xv.y * Wl[(k0 + 1) * 64 + lane];
      hn += xv.z * Wl[(k0 + 2) * 64 + lane];
      hn += xv.w * Wl[(k0 + 3) * 64 + lane];
    }
    ho[(long)v * 64 + lane] = __float2half(dv * hn);
    if (!more) break;
    v = vn; uu = uun; ct = ctn; sv = svn;
  }
}

// layers 2-3: FOUR nodes per wave (quarter q = lane>>4 owns node vA+q; lane
// holds 4 channels as 8B half4). One gather inst covers 4x128B rows.
// LN: layernorm. TR: write dinv*(x@Wn). PS: no h output — pooled atomicAdd into sums.
template <int LN, int TR, int PS>
__global__ void __launch_bounds__(256, 6) k_agg(
    const uint2* __restrict__ h, uint2* __restrict__ xo,
    const int* __restrict__ cnt, const int* __restrict__ bsrc,
    const float* __restrict__ bias, const float* __restrict__ lng,
    const float* __restrict__ lnb, const float* __restrict__ Wn,
    const int* __restrict__ batch, float* __restrict__ sums) {
  __shared__ float Wl[TR ? 4096 : 1];
  __shared__ float xs[1024];  // 16 nodes x 64 channels
  __shared__ int sg[16];
  int t = threadIdx.x;
  if (TR) {
    for (int i = t; i < 4096; i += 256) Wl[i] = Wn[i];
    __syncthreads();
  }
  int w = t >> 6, lane = t & 63;
  int q = lane >> 4, l = lane & 15;  // lane l holds channels 4l..4l+3
  for (int base = blockIdx.x * 16; base < NN; base += NBK2 * 16) {  // block-uniform
    int v = base + w * 4 + q;         // my quarter's node
    int ctL = cnt[v];                 // 4 distinct addrs per wave
    int dL = min(ctL, CAP);
    int m = max(dL, __shfl_xor(dL, 16, 64));
    m = max(m, __shfl_xor(m, 32, 64));
    int degM = __builtin_amdgcn_readfirstlane(m);  // wave-uniform loop bound
    float dv = rsqrtf((float)ctL + 1.0f);
    const int* bp = bsrc + v * CAP;
    uint2 hv2 = h[(long)v * 16 + l];  // self term (8B per lane, 128B per row)
    float4 aA = {0.f, 0.f, 0.f, 0.f}, aB = aA;
    for (int k = 0; k < degM; k += 8) {
      int u0 = (k + 0 < dL) ? bp[k + 0] : -1;  // -1 -> zero guard row
      int u1 = (k + 1 < dL) ? bp[k + 1] : -1;
      int u2 = (k + 2 < dL) ? bp[k + 2] : -1;
      int u3 = (k + 3 < dL) ? bp[k + 3] : -1;
      int u4 = (k + 4 < dL) ? bp[k + 4] : -1;
      int u5 = (k + 5 < dL) ? bp[k + 5] : -1;
      int u6 = (k + 6 < dL) ? bp[k + 6] : -1;
      int u7 = (k + 7 < dL) ? bp[k + 7] : -1;
      uint2 g0 = h[(long)u0 * 16 + l];  // 8 gathers in flight, 4 edges each
      uint2 g1 = h[(long)u1 * 16 + l];
      uint2 g2 = h[(long)u2 * 16 + l];
      uint2 g3 = h[(long)u3 * 16 + l];
      uint2 g4 = h[(long)u4 * 16 + l];
      uint2 g5 = h[(long)u5 * 16 + l];
      uint2 g6 = h[(long)u6 * 16 + l];
      uint2 g7 = h[(long)u7 * 16 + l];
      float4 f0 = h4tof4(g0), f1 = h4tof4(g1), f2 = h4tof4(g2), f3 = h4tof4(g3);
      float4 f4 = h4tof4(g4), f5 = h4tof4(g5), f6 = h4tof4(g6), f7 = h4tof4(g7);
      aA.x += f0.x + f1.x + f2.x + f3.x; aB.x += f4.x + f5.x + f6.x + f7.x;
      aA.y += f0.y + f1.y + f2.y + f3.y; aB.y += f4.y + f5.y + f6.y + f7.y;
      aA.z += f0.z + f1.z + f2.z + f3.z; aB.z += f4.z + f5.z + f6.z + f7.z;
      aA.w += f0.w + f1.w + f2.w + f3.w; aB.w += f4.w + f5.w + f6.w + f7.w;
    }
    float4 hv = h4tof4(hv2);
    float4 bb = ((const float4*)bias)[l];
    float4 val;
    val.x = fmaxf(dv * (aA.x + aB.x + hv.x) + bb.x, 0.0f);
    val.y = fmaxf(dv * (aA.y + aB.y + hv.y) + bb.y, 0.0f);
    val.z = fmaxf(dv * (aA.z + aB.z + hv.z) + bb.z, 0.0f);
    val.w = fmaxf(dv * (aA.w + aB.w + hv.w) + bb.w, 0.0f);
    if (LN) {  // reduce over my 16-lane quarter (16 lanes x 4 channels)
      float r = (val.x + val.y) + (val.z + val.w);
#pragma unroll
      for (int o = 8; o > 0; o >>= 1) r += __shfl_xor(r, o, 64);
      float mu = r * 0.015625f;
      float dx = val.x - mu, dy = val.y - mu, dz = val.z - mu, dw = val.w - mu;
      float q2 = (dx * dx + dy * dy) + (dz * dz + dw * dw);
#pragma unroll
      for (int o = 8; o > 0; o >>= 1) q2 += __shfl_xor(q2, o, 64);
      float rstd = rsqrtf(q2 * 0.015625f + 1e-5f);
      float4 gg = ((const float4*)lng)[l];
      float4 lbv = ((const float4*)lnb)[l];
      val.x = dx * rstd * gg.x + lbv.x;
      val.y = dy * rstd * gg.y + lbv.y;
      val.z = dz * rstd * gg.z + lbv.z;
      val.w = dw * rstd * gg.w + lbv.w;
    }
    int n = w * 4 + q;  // node slot in block (0..15)
    if (TR) {  // h_next' = dinv * (x @ Wnext); quarter-local xs, no barrier
      float* xp = &xs[n * 64];
      ((float4*)xp)[l] = val;
      float4 hn = {0.f, 0.f, 0.f, 0.f};
#pragma unroll
      for (int k0 = 0; k0 < 64; k0 += 4) {
        float4 xv = *(const float4*)(xp + k0);  // quarter-uniform addr -> broadcast
        float4 w0 = ((const float4*)(Wl + (k0 + 0) * 64))[l];
        float4 w1 = ((const float4*)(Wl + (k0 + 1) * 64))[l];
        float4 w2 = ((const float4*)(Wl + (k0 + 2) * 64))[l];
        float4 w3 = ((const float4*)(Wl + (k0 + 3) * 64))[l];
        hn.x += xv.x * w0.x + xv.y * w1.x + xv.z * w2.x + xv.w * w3.x;
        hn.y += xv.x * w0.y + xv.y * w1.y + xv.z * w2.y + xv.w * w3.y;
        hn.z += xv.x * w0.z + xv.y * w1.z + xv.z * w2.z + xv.w * w3.z;
        hn.w += xv.x * w0.w + xv.y * w1.w + xv.z * w2.w + xv.w * w3.w;
      }
      hn.x *= dv; hn.y *= dv; hn.z *= dv; hn.w *= dv;
      xo[(long)v * 16 + l] = f4toh4(hn);
    } else if (PS) {
      // final layer: pooled accumulation. Block = 16 contiguous nodes (batch
      // sorted -> few distinct graphs); run-length flush by wave 0.
      ((float4*)&xs[n * 64])[l] = val;
      if (lane == (q << 4)) sg[n] = batch[v];  // quarter leader
      __syncthreads();
      if (t < 64) {
        float acc = 0.0f;
        int gprev = sg[0];
#pragma unroll
        for (int n2 = 0; n2 < 16; n2++) {
          int gs = sg[n2];
          if (gs != gprev) {
            atomicAdd(&sums[gprev * 64 + t], acc);
            acc = 0.0f;
            gprev = gs;
          }
          acc += xs[n2 * 64 + t];
        }
        atomicAdd(&sums[gprev * 64 + t], acc);
      }
      __syncthreads();  // xs reused next iteration
    } else {
      xo[(long)v * 16 + l] = f4toh4(val);
    }
  }
}

// per-graph mean + 2-layer MLP; one wave per graph
__global__ void k_mlp(const float* __restrict__ sums, const int* __restrict__ goff,
                      const float* __restrict__ pW1, const float* __restrict__ pb1,
                      const float* __restrict__ pW2, const float* __restrict__ pb2,
                      float* __restrict__ out) {
  int lane = threadIdx.x;  // 64
  int g = blockIdx.x;
  float c = (float)(goff[g + 1] - goff[g]);
  float pooled = sums[g * 64 + lane] / fmaxf(c, 1.0f);
  float hv = pb1[lane];
#pragma unroll
  for (int k = 0; k < 64; k++) hv += __shfl(pooled, k, 64) * pW1[k * 64 + lane];
  float ov = pb2[lane];
#pragma unroll
  for (int k = 0; k < 64; k++) ov += __shfl(hv, k, 64) * pW2[k * 64 + lane];
  out[g * 64 + lane] = ov;
}

extern "C" void kernel_launch(void* const* d_in, const int* in_sizes, int n_in,
                              void* d_out, int out_size, void* d_ws, size_t ws_size,
                              hipStream_t stream) {
  const int* node = (const int*)d_in[0];
  const int* src = (const int*)d_in[1];
  const int* dst = (const int*)d_in[2];
  const int* batch = (const int*)d_in[3];
  const float* emb = (const float*)d_in[4];
  const float* W1 = (const float*)d_in[5];
  const float* b1 = (const float*)d_in[6];
  const float* W2 = (const float*)d_in[7];
  const float* b2 = (const float*)d_in[8];
  const float* W3 = (const float*)d_in[9];
  const float* b3 = (const float*)d_in[10];
  const float* g1 = (const float*)d_in[11];
  const float* lb1 = (const float*)d_in[12];
  const float* g2 = (const float*)d_in[13];
  const float* lb2 = (const float*)d_in[14];
  const float* pW1 = (const float*)d_in[15];
  const float* pb1 = (const float*)d_in[16];
  const float* pW2 = (const float*)d_in[17];
  const float* pb2 = (const float*)d_in[18];
  float* out = (float*)d_out;

  // workspace layout (bytes); ws re-poisoned each call -> rebuild everything
  char* w = (char*)d_ws;
  int* cnt = (int*)(w + 0);            // [0, 200000)       zeroed by memset
  float* sums = (float*)(w + 200000);  // [200000, 216384)  zeroed by same memset
  int* bsrc = (int*)(w + 216576);      // NN*CAP+16 ints -> [216576, 13016640)
  int* goff = (int*)(w + 13016640);    // 65 ints
  float4* xe = (float4*)(w + 13017088) + 1;   // guard float4 + 50000 float4
  __half* hA = (__half*)(w + 13817216) + 64;  // guard row + 50000x64 fp16
  __half* hB = (__half*)(w + 20217472) + 64;  // guard row + 50000x64 fp16 (~26.6MB)

  hipMemsetAsync(w, 0, 216384, stream);  // cnt + sums
  k_bucket<<<3125, 256, 0, stream>>>(src, dst, cnt, bsrc);
  k_embed4<<<196, 256, 0, stream>>>(node, emb, cnt, batch, xe, hA, hB, goff);
  k_agg1<<<NBK1, 256, 0, stream>>>(xe, hA, cnt, bsrc, W1, b1, g1, lb1, W2);
  k_agg<1, 1, 0><<<NBK2, 256, 0, stream>>>((const uint2*)hA, (uint2*)hB, cnt, bsrc,
                                           b2, g2, lb2, W3, nullptr, nullptr);
  k_agg<0, 0, 1><<<NBK2, 256, 0, stream>>>((const uint2*)hB, (uint2*)hA, cnt, bsrc,
                                           b3, nullptr, nullptr, nullptr, batch, sums);
  k_mlp<<<64, 64, 0, stream>>>(sums, goff, pW1, pb1, pW2, pb2, out);
}

// Round 13
// 238.680 us; speedup vs baseline: 2.0879x; 2.0879x over previous
//
#include <hip/hip_runtime.h>
#include <hip/hip_fp16.h>

static constexpr int NN = 50000;   // nodes
static constexpr int NE = 800000;  // edges
static constexpr int CAP = 64;     // bucket capacity == wave width (Poisson(16) degrees)
static constexpr int NBK1 = 2048;  // k_agg1 grid, grid-stride
// HID = 64, N_GRAPHS = 64

__device__ __forceinline__ float wsum(float v) {
#pragma unroll
  for (int o = 32; o > 0; o >>= 1) v += __shfl_xor(v, o, 64);
  return v;
}

// one-pass bucketed CSR, 2 edges/thread (int2 loads): slot = atomic rank within
// dst's bucket. No pre-fill; slots >= deg clamped to -1 at read -> zero guard row.
__global__ void k_bucket(const int2* __restrict__ src2, const int2* __restrict__ dst2,
                         int* __restrict__ cnt, int* __restrict__ bsrc) {
  int i = blockIdx.x * 256 + threadIdx.x;
  if (i < NE / 2) {
    int2 d = dst2[i];
    int2 s = src2[i];
    int p0 = atomicAdd(&cnt[d.x], 1);
    if (p0 < CAP) bsrc[d.x * CAP + p0] = s.x;
    int p1 = atomicAdd(&cnt[d.y], 1);
    if (p1 < CAP) bsrc[d.y * CAP + p1] = s.y;
  }
}

// xe[v] = dinv[v] * emb[node[v]]  (4-dim, layer-1 aggregation is linear in x)
// + zero guard rows (xe[-1], hA[-64..-1], hB[-64..-1]) + goff binary searches
__global__ void k_embed4(const int* __restrict__ node, const float* __restrict__ emb,
                         const int* __restrict__ cnt, const int* __restrict__ batch,
                         float4* __restrict__ xe, __half* __restrict__ hA,
                         __half* __restrict__ hB, int* __restrict__ goff) {
  int i = blockIdx.x * 256 + threadIdx.x;
  if (i < NN) {
    float dv = rsqrtf((float)cnt[i] + 1.0f);  // deg includes self-loop
    float4 e = ((const float4*)emb)[node[i]];
    e.x *= dv; e.y *= dv; e.z *= dv; e.w *= dv;
    xe[i] = e;
  } else if (i < NN + 64) {
    int j = i - NN;  // guard rows stay zero through all layers
    hA[-64 + j] = __float2half(0.0f);
    hB[-64 + j] = __float2half(0.0f);
    if (j == 0) xe[-1] = make_float4(0.f, 0.f, 0.f, 0.f);
  } else if (i < NN + 129) {  // g in [0,64]: goff[g] = lower_bound(batch, g)
    int g = i - NN - 64;
    int lo = 0, hi = NN;
    while (lo < hi) {
      int mid = (lo + hi) >> 1;
      lo = (batch[mid] < g) ? mid + 1 : lo;
      hi = (batch[mid] < g) ? hi : mid;
    }
    goff[g] = lo;
  }
}

// layer 1: wave-per-node, LANE-PER-EDGE 4-dim gather. Grid-stride: weights
// staged ONCE per block; next node's idx/cnt/self prefetched before current chain.
__global__ void __launch_bounds__(256) k_agg1(
    const float4* __restrict__ xe, __half* __restrict__ ho,
    const int* __restrict__ cnt, const int* __restrict__ bsrc,
    const float* __restrict__ W1, const float* __restrict__ b1,
    const float* __restrict__ g1, const float* __restrict__ lb1,
    const float* __restrict__ W2) {
  __shared__ float W1s[256];
  __shared__ float Wl[4096];
  __shared__ float xs[256];
  int t = threadIdx.x;
  W1s[t] = W1[t];
  for (int i = t; i < 4096; i += 256) Wl[i] = W2[i];
  __syncthreads();
  int w = t >> 6, lane = t & 63;
  int v = blockIdx.x * 4 + w;  // stride NBK1*4 = 8192
  int uu = bsrc[v * CAP + lane];
  int ct = __builtin_amdgcn_readfirstlane(cnt[v]);
  float4 sv = xe[(long)v];
  while (true) {
    int vn = v + NBK1 * 4;
    bool more = vn < NN;  // wave-uniform
    int uun = 0, ctn = 0;
    float4 svn;
    if (more) {  // prefetch next iteration ahead of current dependency chain
      uun = bsrc[vn * CAP + lane];
      ctn = __builtin_amdgcn_readfirstlane(cnt[vn]);
      svn = xe[(long)vn];
    }
    int deg = min(ct, CAP);
    int u = (lane < deg) ? uu : -1;      // clamp garbage slots -> zero guard row
    float4 y = xe[(long)u];              // 64 scattered 16B gathers in ONE instruction
#pragma unroll
    for (int o = 32; o > 0; o >>= 1) {   // wave-reduce float4
      y.x += __shfl_xor(y.x, o, 64);
      y.y += __shfl_xor(y.y, o, 64);
      y.z += __shfl_xor(y.z, o, 64);
      y.w += __shfl_xor(y.w, o, 64);
    }
    float dv = rsqrtf((float)ct + 1.0f);
    y.x = dv * (y.x + sv.x);
    y.y = dv * (y.y + sv.y);
    y.z = dv * (y.z + sv.z);
    y.w = dv * (y.w + sv.w);
    float val = y.x * W1s[lane] + y.y * W1s[64 + lane] + y.z * W1s[128 + lane] +
                y.w * W1s[192 + lane] + b1[lane];
    val = fmaxf(val, 0.0f);  // relu
    float mu = wsum(val) * 0.015625f;
    float d = val - mu;
    float var = wsum(d * d) * 0.015625f;
    val = d * rsqrtf(var + 1e-5f) * g1[lane] + lb1[lane];
    xs[w * 64 + lane] = val;  // broadcast x for W2 transform (per-wave slot)
    float hn = 0.0f;
    const float* xp = &xs[w * 64];
#pragma unroll
    for (int k0 = 0; k0 < 64; k0 += 4) {
      float4 xv = *(const float4*)(xp + k0);  // wave-uniform addr -> broadcast
      hn += xv.x * Wl[(k0 + 0) * 64 + lane];
      hn += xv.y * Wl[(k0 + 1) * 64 + lane];
      hn += xv.z * Wl[(k0 + 2) * 64 + lane];
      hn += xv.w * Wl[(k0 + 3) * 64 + lane];
    }
    ho[(long)v * 64 + lane] = __float2half(dv * hn);
    if (!more) break;
    v = vn; uu = uun; ct = ctn; sv = svn;
  }
}

// layers 2-3 (R10-proven layout): TWO nodes per wave (lanes 0-31 = node A,
// 32-63 = node B; lane holds 2 channels as half2). One gather inst = 2x128B rows.
// LN: layernorm. TR: write dinv*(x@Wn). PS: no h output — pooled atomicAdd into sums.
template <int LN, int TR, int PS>
__global__ void __launch_bounds__(256) k_agg(
    const __half2* __restrict__ h, __half2* __restrict__ xo,
    const int* __restrict__ cnt, const int* __restrict__ bsrc,
    const float* __restrict__ bias, const float* __restrict__ lng,
    const float* __restrict__ lnb, const float* __restrict__ Wn,
    const int* __restrict__ batch, float* __restrict__ sums) {
  __shared__ float Wl[TR ? 4096 : 1];
  __shared__ float xs[512];
  __shared__ int sg[8];
  int t = threadIdx.x;
  if (TR) {
    for (int i = t; i < 4096; i += 256) Wl[i] = Wn[i];
    __syncthreads();
  }
  int w = t >> 6, lane = t & 63;
  int hb = lane >> 5, l = lane & 31;
  int vA = blockIdx.x * 8 + w * 2;  // 6250*8 = 50000
  int ctA = __builtin_amdgcn_readfirstlane(cnt[vA]);
  int ctB = __builtin_amdgcn_readfirstlane(cnt[vA + 1]);
  int degA = min(ctA, CAP), degB = min(ctB, CAP);
  int degM = max(degA, degB);       // wave-uniform loop bound
  int v = vA + hb;
  int degL = hb ? degB : degA;      // per-lane clamp bound
  const int* bp = bsrc + v * CAP;   // 2 rows per wave, adjacent
  float dv = rsqrtf((float)(hb ? ctB : ctA) + 1.0f);
  float2 hv = __half22float2(h[(long)v * 32 + l]);  // self term
  float2 a0 = {0.f, 0.f}, a1 = a0, a2 = a0, a3 = a0, a4 = a0, a5 = a0, a6 = a0, a7 = a0;
  int x0 = bp[0], x1 = bp[1], x2 = bp[2], x3 = bp[3];
  int x4 = bp[4], x5 = bp[5], x6 = bp[6], x7 = bp[7];
  int u0 = (0 < degL) ? x0 : -1;
  int u1 = (1 < degL) ? x1 : -1;
  int u2 = (2 < degL) ? x2 : -1;
  int u3 = (3 < degL) ? x3 : -1;
  int u4 = (4 < degL) ? x4 : -1;
  int u5 = (5 < degL) ? x5 : -1;
  int u6 = (6 < degL) ? x6 : -1;
  int u7 = (7 < degL) ? x7 : -1;
  for (int k = 0; k < degM; k += 8) {
    float2 g0 = __half22float2(h[(long)u0 * 32 + l]);  // 16 edges in flight
    float2 g1v = __half22float2(h[(long)u1 * 32 + l]);
    float2 g2 = __half22float2(h[(long)u2 * 32 + l]);
    float2 g3 = __half22float2(h[(long)u3 * 32 + l]);
    float2 g4 = __half22float2(h[(long)u4 * 32 + l]);
    float2 g5 = __half22float2(h[(long)u5 * 32 + l]);
    float2 g6 = __half22float2(h[(long)u6 * 32 + l]);
    float2 g7 = __half22float2(h[(long)u7 * 32 + l]);
    x0 = bp[k + 8];  x1 = bp[k + 9];   // prefetch next group (buffer padded +16)
    x2 = bp[k + 10]; x3 = bp[k + 11];
    x4 = bp[k + 12]; x5 = bp[k + 13];
    x6 = bp[k + 14]; x7 = bp[k + 15];
    u0 = (k + 8 < degL) ? x0 : -1;
    u1 = (k + 9 < degL) ? x1 : -1;
    u2 = (k + 10 < degL) ? x2 : -1;
    u3 = (k + 11 < degL) ? x3 : -1;
    u4 = (k + 12 < degL) ? x4 : -1;
    u5 = (k + 13 < degL) ? x5 : -1;
    u6 = (k + 14 < degL) ? x6 : -1;
    u7 = (k + 15 < degL) ? x7 : -1;
    a0.x += g0.x; a0.y += g0.y; a1.x += g1v.x; a1.y += g1v.y;
    a2.x += g2.x; a2.y += g2.y; a3.x += g3.x; a3.y += g3.y;
    a4.x += g4.x; a4.y += g4.y; a5.x += g5.x; a5.y += g5.y;
    a6.x += g6.x; a6.y += g6.y; a7.x += g7.x; a7.y += g7.y;
  }
  float2 s;
  s.x = ((a0.x + a1.x) + (a2.x + a3.x)) + ((a4.x + a5.x) + (a6.x + a7.x)) + hv.x;
  s.y = ((a0.y + a1.y) + (a2.y + a3.y)) + ((a4.y + a5.y) + (a6.y + a7.y)) + hv.y;
  float2 bb = ((const float2*)bias)[l];
  float2 val;
  val.x = fmaxf(dv * s.x + bb.x, 0.0f);
  val.y = fmaxf(dv * s.y + bb.y, 0.0f);
  if (LN) {  // reduce over my half-wave (32 lanes x 2 channels)
    float r = val.x + val.y;
#pragma unroll
    for (int o = 16; o > 0; o >>= 1) r += __shfl_xor(r, o, 64);
    float mu = r * 0.015625f;
    float dx = val.x - mu, dy = val.y - mu;
    float q = dx * dx + dy * dy;
#pragma unroll
    for (int o = 16; o > 0; o >>= 1) q += __shfl_xor(q, o, 64);
    float rstd = rsqrtf(q * 0.015625f + 1e-5f);
    float2 gg = ((const float2*)lng)[l];
    float2 lbv = ((const float2*)lnb)[l];
    val.x = dx * rstd * gg.x + lbv.x;
    val.y = dy * rstd * gg.y + lbv.y;
  }
  if (TR) {  // h_next' = dinv * (x @ Wnext); per-wave xs slots, no barrier
    int n = w * 2 + hb;  // node slot in block (0..7)
    float* xp = &xs[n * 64];
    *(float2*)(xp + 2 * l) = val;
    float2 hn = {0.f, 0.f};
#pragma unroll
    for (int k0 = 0; k0 < 64; k0 += 4) {
      float4 xv = *(const float4*)(xp + k0);  // half-wave-uniform -> broadcast
      float2 w0 = *(const float2*)&Wl[(k0 + 0) * 64 + 2 * l];
      float2 w1 = *(const float2*)&Wl[(k0 + 1) * 64 + 2 * l];
      float2 w2 = *(const float2*)&Wl[(k0 + 2) * 64 + 2 * l];
      float2 w3 = *(const float2*)&Wl[(k0 + 3) * 64 + 2 * l];
      hn.x += xv.x * w0.x; hn.y += xv.x * w0.y;
      hn.x += xv.y * w1.x; hn.y += xv.y * w1.y;
      hn.x += xv.z * w2.x; hn.y += xv.z * w2.y;
      hn.x += xv.w * w3.x; hn.y += xv.w * w3.y;
    }
    xo[(long)v * 32 + l] = __float22half2_rn(make_float2(dv * hn.x, dv * hn.y));
  } else if (PS) {
    // final layer: pooled accumulation. Block = 8 contiguous nodes (batch
    // sorted -> few distinct graphs); run-length flush by wave 0.
    int n = w * 2 + hb;
    *(float2*)&xs[n * 64 + 2 * l] = val;
    if (l == 0) sg[n] = batch[v];
    __syncthreads();
    if (t < 64) {
      float acc = 0.0f;
      int gprev = sg[0];
#pragma unroll
      for (int n2 = 0; n2 < 8; n2++) {
        int gs = sg[n2];
        if (gs != gprev) {
          atomicAdd(&sums[gprev * 64 + t], acc);
          acc = 0.0f;
          gprev = gs;
        }
        acc += xs[n2 * 64 + t];
      }
      atomicAdd(&sums[gprev * 64 + t], acc);
    }
  } else {
    xo[(long)v * 32 + l] = __float22half2_rn(val);
  }
}

// per-graph mean + 2-layer MLP; one wave per graph
__global__ void k_mlp(const float* __restrict__ sums, const int* __restrict__ goff,
                      const float* __restrict__ pW1, const float* __restrict__ pb1,
                      const float* __restrict__ pW2, const float* __restrict__ pb2,
                      float* __restrict__ out) {
  int lane = threadIdx.x;  // 64
  int g = blockIdx.x;
  float c = (float)(goff[g + 1] - goff[g]);
  float pooled = sums[g * 64 + lane] / fmaxf(c, 1.0f);
  float hv = pb1[lane];
#pragma unroll
  for (int k = 0; k < 64; k++) hv += __shfl(pooled, k, 64) * pW1[k * 64 + lane];
  float ov = pb2[lane];
#pragma unroll
  for (int k = 0; k < 64; k++) ov += __shfl(hv, k, 64) * pW2[k * 64 + lane];
  out[g * 64 + lane] = ov;
}

extern "C" void kernel_launch(void* const* d_in, const int* in_sizes, int n_in,
                              void* d_out, int out_size, void* d_ws, size_t ws_size,
                              hipStream_t stream) {
  const int* node = (const int*)d_in[0];
  const int* src = (const int*)d_in[1];
  const int* dst = (const int*)d_in[2];
  const int* batch = (const int*)d_in[3];
  const float* emb = (const float*)d_in[4];
  const float* W1 = (const float*)d_in[5];
  const float* b1 = (const float*)d_in[6];
  const float* W2 = (const float*)d_in[7];
  const float* b2 = (const float*)d_in[8];
  const float* W3 = (const float*)d_in[9];
  const float* b3 = (const float*)d_in[10];
  const float* g1 = (const float*)d_in[11];
  const float* lb1 = (const float*)d_in[12];
  const float* g2 = (const float*)d_in[13];
  const float* lb2 = (const float*)d_in[14];
  const float* pW1 = (const float*)d_in[15];
  const float* pb1 = (const float*)d_in[16];
  const float* pW2 = (const float*)d_in[17];
  const float* pb2 = (const float*)d_in[18];
  float* out = (float*)d_out;

  // workspace layout (bytes); ws re-poisoned each call -> rebuild everything
  char* w = (char*)d_ws;
  int* cnt = (int*)(w + 0);            // [0, 200000)       zeroed by memset
  float* sums = (float*)(w + 200000);  // [200000, 216384)  zeroed by same memset
  int* bsrc = (int*)(w + 216576);      // NN*CAP+16 ints -> [216576, 13016640)
  int* goff = (int*)(w + 13016640);    // 65 ints
  float4* xe = (float4*)(w + 13017088) + 1;   // guard float4 + 50000 float4
  __half* hA = (__half*)(w + 13817216) + 64;  // guard row + 50000x64 fp16
  __half* hB = (__half*)(w + 20217472) + 64;  // guard row + 50000x64 fp16 (~26.6MB)

  hipMemsetAsync(w, 0, 216384, stream);  // cnt + sums
  k_bucket<<<1563, 256, 0, stream>>>((const int2*)src, (const int2*)dst, cnt, bsrc);
  k_embed4<<<196, 256, 0, stream>>>(node, emb, cnt, batch, xe, hA, hB, goff);
  k_agg1<<<NBK1, 256, 0, stream>>>(xe, hA, cnt, bsrc, W1, b1, g1, lb1, W2);
  k_agg<1, 1, 0><<<6250, 256, 0, stream>>>((const __half2*)hA, (__half2*)hB, cnt, bsrc,
                                           b2, g2, lb2, W3, nullptr, nullptr);
  k_agg<0, 0, 1><<<6250, 256, 0, stream>>>((const __half2*)hB, (__half2*)hA, cnt, bsrc,
                                           b3, nullptr, nullptr, nullptr, batch, sums);
  k_mlp<<<64, 64, 0, stream>>>(sums, goff, pW1, pb1, pW2, pb2, out);
}

// Round 14
// 217.340 us; speedup vs baseline: 2.2929x; 1.0982x over previous
//
#include <hip/hip_runtime.h>
#include <hip/hip_fp16.h>

static constexpr int NN = 50000;   // nodes
static constexpr int NE = 800000;  // edges
static constexpr int CAP = 64;     // bucket capacity (Poisson(16) degrees)
static constexpr int NBIN = 391;   // ceil(NN/128): 128-node bins
static constexpr int BCAP = 3072;  // per-bin edge capacity (mean 2046, >20 sigma)
static constexpr int NBK1 = 2048;  // k_agg1 grid, grid-stride
// HID = 64, N_GRAPHS = 64

__device__ __forceinline__ float wsum(float v) {
#pragma unroll
  for (int o = 32; o > 0; o >>= 1) v += __shfl_xor(v, o, 64);
  return v;
}

// pass 1: bin edges by dst>>7. LDS histogram -> one global atomicAdd per
// (block,bin) -> per-bin runs written near-contiguously (kills the 49MB
// write-amplification of the old random 4B bucket scatter).
__global__ void __launch_bounds__(256) k_bin(
    const int* __restrict__ src, const int* __restrict__ dst,
    int* __restrict__ gbin_cnt, int2* __restrict__ gbin) {
  __shared__ int hist[NBIN];
  __shared__ int base[NBIN];
  int t = threadIdx.x;
  for (int i = t; i < NBIN; i += 256) hist[i] = 0;
  __syncthreads();
  int e0 = blockIdx.x * 2048;
  int s[8], d[8], r[8];
#pragma unroll
  for (int j = 0; j < 8; j++) {
    int idx = e0 + j * 256 + t;  // coalesced
    if (idx < NE) {
      s[j] = src[idx];
      d[j] = dst[idx];
      r[j] = atomicAdd(&hist[d[j] >> 7], 1);  // LDS atomic rank
    }
  }
  __syncthreads();
  for (int i = t; i < NBIN; i += 256) {
    int h = hist[i];
    base[i] = h ? atomicAdd(&gbin_cnt[i], h) : 0;  // reserve global run
  }
  __syncthreads();
#pragma unroll
  for (int j = 0; j < 8; j++) {
    int idx = e0 + j * 256 + t;
    if (idx < NE) {
      int bin = d[j] >> 7;
      int pos = base[bin] + r[j];
      if (pos < BCAP) gbin[bin * BCAP + pos] = make_int2(s[j], d[j]);
    }
  }
}

// pass 2: block b = bin b (128 nodes). Re-bucket bin's edges in LDS (LDS
// atomics), then flush cnt + bucket rows COALESCED (each line written once by
// one block). Fused: xe[v] = dinv[v]*emb[node[v]] for the block's nodes;
// guard rows (xe[-1], hA/hB[-64..-1]) in block 0.
__global__ void __launch_bounds__(256) k_csr(
    const int* __restrict__ gbin_cnt, const int2* __restrict__ gbin,
    const int* __restrict__ node, const float* __restrict__ emb,
    int* __restrict__ cnt, int* __restrict__ bsrc, float4* __restrict__ xe,
    __half* __restrict__ hA, __half* __restrict__ hB) {
  __shared__ int lcnt[128];
  __shared__ int lbuck[128 * CAP];  // 32 KB
  int t = threadIdx.x;
  int b = blockIdx.x;
  if (t < 128) lcnt[t] = 0;
  __syncthreads();
  int n = min(gbin_cnt[b], BCAP);
  for (int i = t; i < n; i += 256) {
    int2 e = gbin[b * BCAP + i];
    int dl = e.y & 127;
    int p = atomicAdd(&lcnt[dl], 1);  // LDS atomic, 128-way spread
    if (p < CAP) lbuck[dl * CAP + p] = e.x;
  }
  __syncthreads();
  int v0 = b * 128;
  int nrows = min(128, NN - v0);  // last bin has 80 nodes
  if (t < nrows) {
    int v = v0 + t;
    int c = lcnt[t];
    cnt[v] = c;
    float dv = rsqrtf((float)c + 1.0f);  // deg includes self-loop
    float4 e = ((const float4*)emb)[node[v]];
    e.x *= dv; e.y *= dv; e.z *= dv; e.w *= dv;
    xe[v] = e;
  }
  for (int i = t; i < nrows * CAP; i += 256) bsrc[v0 * CAP + i] = lbuck[i];
  if (b == 0 && t < 64) {  // guard rows stay zero through all layers
    hA[-64 + t] = __float2half(0.0f);
    hB[-64 + t] = __float2half(0.0f);
    if (t == 0) xe[-1] = make_float4(0.f, 0.f, 0.f, 0.f);
  }
}

// layer 1: wave-per-node, LANE-PER-EDGE 4-dim gather. Grid-stride: weights
// staged ONCE per block; next node's idx/cnt/self prefetched before current chain.
__global__ void __launch_bounds__(256) k_agg1(
    const float4* __restrict__ xe, __half* __restrict__ ho,
    const int* __restrict__ cnt, const int* __restrict__ bsrc,
    const float* __restrict__ W1, const float* __restrict__ b1,
    const float* __restrict__ g1, const float* __restrict__ lb1,
    const float* __restrict__ W2) {
  __shared__ float W1s[256];
  __shared__ float Wl[4096];
  __shared__ float xs[256];
  int t = threadIdx.x;
  W1s[t] = W1[t];
  for (int i = t; i < 4096; i += 256) Wl[i] = W2[i];
  __syncthreads();
  int w = t >> 6, lane = t & 63;
  int v = blockIdx.x * 4 + w;  // stride NBK1*4 = 8192
  int uu = bsrc[v * CAP + lane];
  int ct = __builtin_amdgcn_readfirstlane(cnt[v]);
  float4 sv = xe[(long)v];
  while (true) {
    int vn = v + NBK1 * 4;
    bool more = vn < NN;  // wave-uniform
    int uun = 0, ctn = 0;
    float4 svn;
    if (more) {  // prefetch next iteration ahead of current dependency chain
      uun = bsrc[vn * CAP + lane];
      ctn = __builtin_amdgcn_readfirstlane(cnt[vn]);
      svn = xe[(long)vn];
    }
    int deg = min(ct, CAP);
    int u = (lane < deg) ? uu : -1;      // clamp garbage slots -> zero guard row
    float4 y = xe[(long)u];              // 64 scattered 16B gathers in ONE instruction
#pragma unroll
    for (int o = 32; o > 0; o >>= 1) {   // wave-reduce float4
      y.x += __shfl_xor(y.x, o, 64);
      y.y += __shfl_xor(y.y, o, 64);
      y.z += __shfl_xor(y.z, o, 64);
      y.w += __shfl_xor(y.w, o, 64);
    }
    float dv = rsqrtf((float)ct + 1.0f);
    y.x = dv * (y.x + sv.x);
    y.y = dv * (y.y + sv.y);
    y.z = dv * (y.z + sv.z);
    y.w = dv * (y.w + sv.w);
    float val = y.x * W1s[lane] + y.y * W1s[64 + lane] + y.z * W1s[128 + lane] +
                y.w * W1s[192 + lane] + b1[lane];
    val = fmaxf(val, 0.0f);  // relu
    float mu = wsum(val) * 0.015625f;
    float d = val - mu;
    float var = wsum(d * d) * 0.015625f;
    val = d * rsqrtf(var + 1e-5f) * g1[lane] + lb1[lane];
    xs[w * 64 + lane] = val;  // broadcast x for W2 transform (per-wave slot)
    float hn = 0.0f;
    const float* xp = &xs[w * 64];
#pragma unroll
    for (int k0 = 0; k0 < 64; k0 += 4) {
      float4 xv = *(const float4*)(xp + k0);  // wave-uniform addr -> broadcast
      hn += xv.x * Wl[(k0 + 0) * 64 + lane];
      hn += xv.y * Wl[(k0 + 1) * 64 + lane];
      hn += xv.z * Wl[(k0 + 2) * 64 + lane];
      hn += xv.w * Wl[(k0 + 3) * 64 + lane];
    }
    ho[(long)v * 64 + lane] = __float2half(dv * hn);
    if (!more) break;
    v = vn; uu = uun; ct = ctn; sv = svn;
  }
}

// layers 2-3 (R10-proven layout): TWO nodes per wave (lanes 0-31 = node A,
// 32-63 = node B; lane holds 2 channels as half2). One gather inst = 2x128B rows.
// LN: layernorm. TR: write dinv*(x@Wn). PS: no h output — pooled atomicAdd into sums.
template <int LN, int TR, int PS>
__global__ void __launch_bounds__(256) k_agg(
    const __half2* __restrict__ h, __half2* __restrict__ xo,
    const int* __restrict__ cnt, const int* __restrict__ bsrc,
    const float* __restrict__ bias, const float* __restrict__ lng,
    const float* __restrict__ lnb, const float* __restrict__ Wn,
    const int* __restrict__ batch, float* __restrict__ sums) {
  __shared__ float Wl[TR ? 4096 : 1];
  __shared__ float xs[512];
  __shared__ int sg[8];
  int t = threadIdx.x;
  if (TR) {
    for (int i = t; i < 4096; i += 256) Wl[i] = Wn[i];
    __syncthreads();
  }
  int w = t >> 6, lane = t & 63;
  int hb = lane >> 5, l = lane & 31;
  int vA = blockIdx.x * 8 + w * 2;  // 6250*8 = 50000
  int ctA = __builtin_amdgcn_readfirstlane(cnt[vA]);
  int ctB = __builtin_amdgcn_readfirstlane(cnt[vA + 1]);
  int degA = min(ctA, CAP), degB = min(ctB, CAP);
  int degM = max(degA, degB);       // wave-uniform loop bound
  int v = vA + hb;
  int degL = hb ? degB : degA;      // per-lane clamp bound
  const int* bp = bsrc + v * CAP;   // 2 rows per wave, adjacent
  float dv = rsqrtf((float)(hb ? ctB : ctA) + 1.0f);
  float2 hv = __half22float2(h[(long)v * 32 + l]);  // self term
  float2 a0 = {0.f, 0.f}, a1 = a0, a2 = a0, a3 = a0, a4 = a0, a5 = a0, a6 = a0, a7 = a0;
  int x0 = bp[0], x1 = bp[1], x2 = bp[2], x3 = bp[3];
  int x4 = bp[4], x5 = bp[5], x6 = bp[6], x7 = bp[7];
  int u0 = (0 < degL) ? x0 : -1;
  int u1 = (1 < degL) ? x1 : -1;
  int u2 = (2 < degL) ? x2 : -1;
  int u3 = (3 < degL) ? x3 : -1;
  int u4 = (4 < degL) ? x4 : -1;
  int u5 = (5 < degL) ? x5 : -1;
  int u6 = (6 < degL) ? x6 : -1;
  int u7 = (7 < degL) ? x7 : -1;
  for (int k = 0; k < degM; k += 8) {
    float2 g0 = __half22float2(h[(long)u0 * 32 + l]);  // 16 edges in flight
    float2 g1v = __half22float2(h[(long)u1 * 32 + l]);
    float2 g2 = __half22float2(h[(long)u2 * 32 + l]);
    float2 g3 = __half22float2(h[(long)u3 * 32 + l]);
    float2 g4 = __half22float2(h[(long)u4 * 32 + l]);
    float2 g5 = __half22float2(h[(long)u5 * 32 + l]);
    float2 g6 = __half22float2(h[(long)u6 * 32 + l]);
    float2 g7 = __half22float2(h[(long)u7 * 32 + l]);
    x0 = bp[k + 8];  x1 = bp[k + 9];   // prefetch next group (buffer padded +16)
    x2 = bp[k + 10]; x3 = bp[k + 11];
    x4 = bp[k + 12]; x5 = bp[k + 13];
    x6 = bp[k + 14]; x7 = bp[k + 15];
    u0 = (k + 8 < degL) ? x0 : -1;
    u1 = (k + 9 < degL) ? x1 : -1;
    u2 = (k + 10 < degL) ? x2 : -1;
    u3 = (k + 11 < degL) ? x3 : -1;
    u4 = (k + 12 < degL) ? x4 : -1;
    u5 = (k + 13 < degL) ? x5 : -1;
    u6 = (k + 14 < degL) ? x6 : -1;
    u7 = (k + 15 < degL) ? x7 : -1;
    a0.x += g0.x; a0.y += g0.y; a1.x += g1v.x; a1.y += g1v.y;
    a2.x += g2.x; a2.y += g2.y; a3.x += g3.x; a3.y += g3.y;
    a4.x += g4.x; a4.y += g4.y; a5.x += g5.x; a5.y += g5.y;
    a6.x += g6.x; a6.y += g6.y; a7.x += g7.x; a7.y += g7.y;
  }
  float2 s;
  s.x = ((a0.x + a1.x) + (a2.x + a3.x)) + ((a4.x + a5.x) + (a6.x + a7.x)) + hv.x;
  s.y = ((a0.y + a1.y) + (a2.y + a3.y)) + ((a4.y + a5.y) + (a6.y + a7.y)) + hv.y;
  float2 bb = ((const float2*)bias)[l];
  float2 val;
  val.x = fmaxf(dv * s.x + bb.x, 0.0f);
  val.y = fmaxf(dv * s.y + bb.y, 0.0f);
  if (LN) {  // reduce over my half-wave (32 lanes x 2 channels)
    float r = val.x + val.y;
#pragma unroll
    for (int o = 16; o > 0; o >>= 1) r += __shfl_xor(r, o, 64);
    float mu = r * 0.015625f;
    float dx = val.x - mu, dy = val.y - mu;
    float q = dx * dx + dy * dy;
#pragma unroll
    for (int o = 16; o > 0; o >>= 1) q += __shfl_xor(q, o, 64);
    float rstd = rsqrtf(q * 0.015625f + 1e-5f);
    float2 gg = ((const float2*)lng)[l];
    float2 lbv = ((const float2*)lnb)[l];
    val.x = dx * rstd * gg.x + lbv.x;
    val.y = dy * rstd * gg.y + lbv.y;
  }
  if (TR) {  // h_next' = dinv * (x @ Wnext); per-wave xs slots, no barrier
    int n = w * 2 + hb;  // node slot in block (0..7)
    float* xp = &xs[n * 64];
    *(float2*)(xp + 2 * l) = val;
    float2 hn = {0.f, 0.f};
#pragma unroll
    for (int k0 = 0; k0 < 64; k0 += 4) {
      float4 xv = *(const float4*)(xp + k0);  // half-wave-uniform -> broadcast
      float2 w0 = *(const float2*)&Wl[(k0 + 0) * 64 + 2 * l];
      float2 w1 = *(const float2*)&Wl[(k0 + 1) * 64 + 2 * l];
      float2 w2 = *(const float2*)&Wl[(k0 + 2) * 64 + 2 * l];
      float2 w3 = *(const float2*)&Wl[(k0 + 3) * 64 + 2 * l];
      hn.x += xv.x * w0.x; hn.y += xv.x * w0.y;
      hn.x += xv.y * w1.x; hn.y += xv.y * w1.y;
      hn.x += xv.z * w2.x; hn.y += xv.z * w2.y;
      hn.x += xv.w * w3.x; hn.y += xv.w * w3.y;
    }
    xo[(long)v * 32 + l] = __float22half2_rn(make_float2(dv * hn.x, dv * hn.y));
  } else if (PS) {
    // final layer: pooled accumulation. Block = 8 contiguous nodes (batch
    // sorted -> few distinct graphs); run-length flush by wave 0.
    int n = w * 2 + hb;
    *(float2*)&xs[n * 64 + 2 * l] = val;
    if (l == 0) sg[n] = batch[v];
    __syncthreads();
    if (t < 64) {
      float acc = 0.0f;
      int gprev = sg[0];
#pragma unroll
      for (int n2 = 0; n2 < 8; n2++) {
        int gs = sg[n2];
        if (gs != gprev) {
          atomicAdd(&sums[gprev * 64 + t], acc);
          acc = 0.0f;
          gprev = gs;
        }
        acc += xs[n2 * 64 + t];
      }
      atomicAdd(&sums[gprev * 64 + t], acc);
    }
  } else {
    xo[(long)v * 32 + l] = __float22half2_rn(val);
  }
}

// per-graph mean + 2-layer MLP; one wave per graph. goff computed inline
// (batch sorted -> lower_bound binary search; wave-uniform scalar loads).
__global__ void k_mlp(const float* __restrict__ sums, const int* __restrict__ batch,
                      const float* __restrict__ pW1, const float* __restrict__ pb1,
                      const float* __restrict__ pW2, const float* __restrict__ pb2,
                      float* __restrict__ out) {
  int lane = threadIdx.x;  // 64
  int g = blockIdx.x;
  int lo = 0, hi = NN;
  while (lo < hi) {  // s0 = lower_bound(batch, g)
    int mid = (lo + hi) >> 1;
    lo = (batch[mid] < g) ? mid + 1 : lo;
    hi = (batch[mid] < g) ? hi : mid;
  }
  int s0 = lo;
  hi = NN;
  while (lo < hi) {  // s1 = lower_bound(batch, g+1)
    int mid = (lo + hi) >> 1;
    lo = (batch[mid] < g + 1) ? mid + 1 : lo;
    hi = (batch[mid] < g + 1) ? hi : mid;
  }
  float c = (float)(lo - s0);
  float pooled = sums[g * 64 + lane] / fmaxf(c, 1.0f);
  float hv = pb1[lane];
#pragma unroll
  for (int k = 0; k < 64; k++) hv += __shfl(pooled, k, 64) * pW1[k * 64 + lane];
  float ov = pb2[lane];
#pragma unroll
  for (int k = 0; k < 64; k++) ov += __shfl(hv, k, 64) * pW2[k * 64 + lane];
  out[g * 64 + lane] = ov;
}

extern "C" void kernel_launch(void* const* d_in, const int* in_sizes, int n_in,
                              void* d_out, int out_size, void* d_ws, size_t ws_size,
                              hipStream_t stream) {
  const int* node = (const int*)d_in[0];
  const int* src = (const int*)d_in[1];
  const int* dst = (const int*)d_in[2];
  const int* batch = (const int*)d_in[3];
  const float* emb = (const float*)d_in[4];
  const float* W1 = (const float*)d_in[5];
  const float* b1 = (const float*)d_in[6];
  const float* W2 = (const float*)d_in[7];
  const float* b2 = (const float*)d_in[8];
  const float* W3 = (const float*)d_in[9];
  const float* b3 = (const float*)d_in[10];
  const float* g1 = (const float*)d_in[11];
  const float* lb1 = (const float*)d_in[12];
  const float* g2 = (const float*)d_in[13];
  const float* lb2 = (const float*)d_in[14];
  const float* pW1 = (const float*)d_in[15];
  const float* pb1 = (const float*)d_in[16];
  const float* pW2 = (const float*)d_in[17];
  const float* pb2 = (const float*)d_in[18];
  float* out = (float*)d_out;

  // workspace layout (bytes); ws re-poisoned each call -> rebuild everything
  char* w = (char*)d_ws;
  int* gbin_cnt = (int*)(w + 0);       // [0, 1564) zeroed by memset (pad to 1792)
  float* sums = (float*)(w + 1792);    // [1792, 18176) zeroed by same memset
  int* cnt = (int*)(w + 18432);        // 50000 ints -> [18432, 218432)
  int* bsrc = (int*)(w + 218432);      // NN*CAP+16 ints -> [218432, 13018496)
  int2* gbin = (int2*)(w + 13018624);  // NBIN*BCAP int2 -> [13018624, 22627840)
  float4* xe = (float4*)(w + 22627840) + 1;   // guard float4 + 50000 float4
  __half* hA = (__half*)(w + 23428096) + 64;  // guard row + 50000x64 fp16
  __half* hB = (__half*)(w + 29828352) + 64;  // guard row + 50000x64 fp16 (~36.2MB)

  hipMemsetAsync(w, 0, 18176, stream);  // gbin_cnt + sums
  k_bin<<<391, 256, 0, stream>>>(src, dst, gbin_cnt, gbin);
  k_csr<<<NBIN, 256, 0, stream>>>(gbin_cnt, gbin, node, emb, cnt, bsrc, xe, hA, hB);
  k_agg1<<<NBK1, 256, 0, stream>>>(xe, hA, cnt, bsrc, W1, b1, g1, lb1, W2);
  k_agg<1, 1, 0><<<6250, 256, 0, stream>>>((const __half2*)hA, (__half2*)hB, cnt, bsrc,
                                           b2, g2, lb2, W3, nullptr, nullptr);
  k_agg<0, 0, 1><<<6250, 256, 0, stream>>>((const __half2*)hB, (__half2*)hA, cnt, bsrc,
                                           b3, nullptr, nullptr, nullptr, batch, sums);
  k_mlp<<<64, 64, 0, stream>>>(sums, batch, pW1, pb1, pW2, pb2, out);
}